// Round 2
// baseline (423.745 us; speedup 1.0000x reference)
//
#include <hip/hip_runtime.h>
#include <hip/hip_bf16.h>

// EmbeddingBagList: T=26, V=1000, D=128, B=8192, NNZ=409600, mode=sum, fp32.
// Round-7: segmented-sum via MFMA (round-6 structure, tr-read address FIXED).
// One wave owns 16 consecutive bags, streams the contiguous index window
// [off[g0], off[g0+16]) in 32-row batches:
//   gather 8x(4 rows x 256B bf16) -> LDS [4x16]-subtiled -> ds_read_b64_tr_b16
//   K-major B-fragments -> mfma_f32_16x16x32_bf16(A = 0/1 segment mask, B, acc)
// tr_b16 semantics (m156-derived): each lane fetches 64b at ITS OWN address,
// then a fixed permute within each 16-lane group: out[s][j] = mem[addr[4j+(s>>2)]
// + 2*(s&3)]. So a group reads a [4][16] row-major bf16 tile via addr = T + s*8
// (8 B/lane, linear) and receives column s. Round-6 used T + s*2 -> garbage.
// A and B fragments share one (lane,elem)->k map (k = 8q+e), so the contraction
// is correct for any true hardware k-ordering; D layout is the m89-verified
// col=lane&15, row=(lane>>4)*4+reg.

#define T_ 26
#define V_ 1000
#define VP_ 1001          // padded rows: row V_ is an all-zero sentinel
#define D_ 128
#define B_ 8192
#define NNZ_ 409600

typedef short s4v  __attribute__((ext_vector_type(4)));
typedef short s8v  __attribute__((ext_vector_type(8)));
typedef float f32x4 __attribute__((ext_vector_type(4)));
typedef unsigned int u32x4v __attribute__((ext_vector_type(4)));

__device__ __forceinline__ unsigned short f2bf(float f) {
    __hip_bfloat16 b = __float2bfloat16(f);   // RNE
    return *reinterpret_cast<unsigned short*>(&b);
}

// ---- pre-pass: fp32 weights -> bf16 rows in workspace (+ zero sentinel row) ----
__global__ __launch_bounds__(256) void convert_kernel(
    const float* __restrict__ weights, uint4* __restrict__ wbf)
{
    const int u = blockIdx.x * 256 + threadIdx.x;   // one uint4 (8 dims) per thread
    const int total = T_ * VP_ * 16;
    if (u >= total) return;
    const int s  = u & 15;              // 16B slot in row
    const int rv = (u >> 4) % VP_;      // padded row
    const int t  = u / (VP_ * 16);      // table
    uint4 pk = make_uint4(0u, 0u, 0u, 0u);
    if (rv < V_) {
        const float* src = weights + ((size_t)t * V_ + rv) * D_ + s * 8;
        const float4 a = ((const float4*)src)[0];
        const float4 b = ((const float4*)src)[1];
        pk.x = ((unsigned)f2bf(a.y) << 16) | f2bf(a.x);
        pk.y = ((unsigned)f2bf(a.w) << 16) | f2bf(a.z);
        pk.z = ((unsigned)f2bf(b.y) << 16) | f2bf(b.x);
        pk.w = ((unsigned)f2bf(b.w) << 16) | f2bf(b.z);
    }
    wbf[u] = pk;
}

// hardware transpose-read: group of 16 lanes, addr = tile_base + s*8 (linear),
// delivers column s of the [4][16] row-major bf16 tile to lane s.
#define TRRD(dst, addr, OFFLIT) \
    asm volatile("ds_read_b64_tr_b16 %0, %1 offset:" OFFLIT : "=v"(dst) : "v"(addr))

#define MFMA16(a, b, c) __builtin_amdgcn_mfma_f32_16x16x32_bf16((a), (b), (c), 0, 0, 0)
#define CAT8(lo, hi) __builtin_shufflevector((lo), (hi), 0, 1, 2, 3, 4, 5, 6, 7)

__global__ __launch_bounds__(256, 4) void embag_mfma_kernel(
    const uint4* __restrict__ wbf,       // [T, VP_, 16] bf16 rows
    const int*   __restrict__ indices,   // [T, NNZ]
    const int*   __restrict__ offsets,   // [T, B]
    float*       __restrict__ out)       // [T, B, D]
{
    // 8 KB per wave: 64 tiles of [4 rows][16 dims] bf16 (=128 B each).
    // tile(G = row>>2, c = dimchunk) at byte (G*8 + c)*128.
    __shared__ uint4 smem4[4 * 512];

    const int bid   = blockIdx.x;
    const int xcd   = bid & 7;        // dispatch round-robins blocks over 8 XCDs
    const int r_    = bid >> 3;
    const int tslot = r_ & 3;
    const int chunk = r_ >> 2;        // 0..127
    const int t     = xcd + 8 * tslot;
    if (t >= T_) return;

    const int wave = threadIdx.x >> 6;
    const int lane = threadIdx.x & 63;
    const int q    = lane >> 4;       // lane group 0..3
    const int s    = lane & 15;       // lane-in-group 0..15

    const int grp = chunk * 4 + wave; // 0..511
    const int g0  = grp * 16;         // first bag of this wave's 16-bag group

    // bag boundaries: lane i (=s) owns bag g0+i with range [lo, hi)
    const int* off = offsets + t * B_;
    const int oi = g0 + lane;
    int o_l = 0;
    if (lane <= 16) o_l = (oi < B_) ? off[oi] : NNZ_;   // off[B_] := NNZ_
    const int lo       = __shfl(o_l, s);
    const int hi       = __shfl(o_l, s + 1);
    const unsigned ulen = (unsigned)(hi - lo);
    const int wstart   = __shfl(o_l, 0);
    const int wend     = __shfl(o_l, 16);

    const uint4* wt  = wbf + (size_t)t * VP_ * 16;
    const int*   ind = indices + (size_t)t * NNZ_;

    // LDS addressing.
    // Write: lane(q,s) holds row 4j+q, dims 8s..8s+7 of load j ->
    //   uint4 index j*64 + (s>>1)*8 + q*2 + (s&1)
    //   (byte j*1024 + (s>>1)*128 + q*32 + (s&1)*16 = tile(j, s>>1) row q half s&1).
    // Read (tr): group q covers k-rows 8q..8q+7 = tiles G=2q (u0) and G=2q+1 (u1);
    //   chunk c tile base = (G*8 + c)*128; per-lane addr = base + s*8.
    const unsigned smem_base = (unsigned)(uintptr_t)(&smem4[0]);  // low-32 = LDS offset
    uint4* myw = smem4 + wave * 512 + (s >> 1) * 8 + q * 2 + (s & 1);
    const unsigned ra = smem_base + (wave << 13) + (q << 11) + (s << 3);

    f32x4 acc[8];
    #pragma unroll
    for (int c = 0; c < 8; ++c) acc[c] = f32x4{0.f, 0.f, 0.f, 0.f};

    for (int wb = wstart; wb < wend; wb += 64) {
        const int p = wb + lane;
        const int myidx = (p < NNZ_) ? ind[p] : V_;   // sentinel beyond table end

        for (int kb = 0; kb < 64 && wb + kb < wend; kb += 32) {
            const int pb = wb + kb;

            // gather 8 x (4 rows x 256B); rows beyond bag ranges are masked by A
            uint4 rr[8];
            #pragma unroll
            for (int j = 0; j < 8; ++j) {
                const int ij = __shfl(myidx, kb + 4 * j + q);
                rr[j] = wt[(size_t)ij * 16 + s];
            }

            // build A mask while the gathers fly: A[i=s][k=q*8+e] = (lo <= pb+k < hi)
            const int rel = pb + q * 8 - lo;
            u32x4v mu;
            #pragma unroll
            for (int pr = 0; pr < 4; ++pr) {
                const unsigned a0 = ((unsigned)(rel + 2 * pr)     < ulen) ? 0x00003F80u : 0u;
                const unsigned a1 = ((unsigned)(rel + 2 * pr + 1) < ulen) ? 0x3F800000u : 0u;
                mu[pr] = a0 | a1;
            }
            const s8v amask = __builtin_bit_cast(s8v, mu);

            // stage to LDS (compiler inserts vmcnt waits before the stores)
            #pragma unroll
            for (int j = 0; j < 8; ++j) myw[j * 64] = rr[j];
            asm volatile("s_waitcnt lgkmcnt(0)" ::: "memory");
            __builtin_amdgcn_sched_barrier(0);

            // chunks 0..3
            s4v u0, u1, u2, u3, u4, u5, u6, u7;
            TRRD(u0, ra, "0");    TRRD(u1, ra, "1024");
            TRRD(u2, ra, "128");  TRRD(u3, ra, "1152");
            TRRD(u4, ra, "256");  TRRD(u5, ra, "1280");
            TRRD(u6, ra, "384");  TRRD(u7, ra, "1408");
            asm volatile("s_waitcnt lgkmcnt(0)" ::: "memory");
            __builtin_amdgcn_sched_barrier(0);
            acc[0] = MFMA16(amask, CAT8(u0, u1), acc[0]);
            acc[1] = MFMA16(amask, CAT8(u2, u3), acc[1]);
            acc[2] = MFMA16(amask, CAT8(u4, u5), acc[2]);
            acc[3] = MFMA16(amask, CAT8(u6, u7), acc[3]);

            // chunks 4..7
            TRRD(u0, ra, "512");  TRRD(u1, ra, "1536");
            TRRD(u2, ra, "640");  TRRD(u3, ra, "1664");
            TRRD(u4, ra, "768");  TRRD(u5, ra, "1792");
            TRRD(u6, ra, "896");  TRRD(u7, ra, "1920");
            asm volatile("s_waitcnt lgkmcnt(0)" ::: "memory");
            __builtin_amdgcn_sched_barrier(0);
            acc[4] = MFMA16(amask, CAT8(u0, u1), acc[4]);
            acc[5] = MFMA16(amask, CAT8(u2, u3), acc[5]);
            acc[6] = MFMA16(amask, CAT8(u4, u5), acc[6]);
            acc[7] = MFMA16(amask, CAT8(u6, u7), acc[7]);
        }
    }

    // D layout (m89): col = lane&15 (dim-in-chunk), row = (lane>>4)*4 + reg (bag)
    float* outt = out + ((size_t)t * B_ + g0) * D_;
    #pragma unroll
    for (int c = 0; c < 8; ++c) {
        #pragma unroll
        for (int r2 = 0; r2 < 4; ++r2) {
            outt[(size_t)(q * 4 + r2) * D_ + c * 16 + s] = acc[c][r2];
        }
    }
}

// ---- fallback: round-3 fp32 gather (used only if ws_size is too small) ----
__global__ __launch_bounds__(256) void embag_fp32_kernel(
    const float* __restrict__ weights,
    const int*   __restrict__ indices,
    const int*   __restrict__ offsets,
    float*       __restrict__ out)
{
    const int bid   = blockIdx.x;
    const int xcd   = bid & 7;
    const int r     = bid >> 3;
    const int tslot = r & 3;
    const int chunk = r >> 2;
    const int t     = xcd + 8 * tslot;
    if (t >= T_) return;

    const int wave = threadIdx.x >> 6;
    const int lane = threadIdx.x & 63;
    const int bag  = chunk * 4 + wave;

    const int* off = offsets + t * B_;
    const int start = off[bag];
    const int end   = (bag == B_ - 1) ? NNZ_ : off[bag + 1];

    const float* wt  = weights + (size_t)t * V_ * D_;
    const int*   ind = indices + (size_t)t * NNZ_;

    const int half  = lane >> 5;
    const int dl    = lane & 31;
    const int col   = dl * 4;
    const int lbase = half << 5;

    float4 acc0 = make_float4(0.f, 0.f, 0.f, 0.f);
    float4 acc1 = make_float4(0.f, 0.f, 0.f, 0.f);

    for (int base = start; base < end; base += 64) {
        const int cnt = (end - base < 64) ? (end - base) : 64;
        const int rowload = (dl << 1) + half;
        int myidx = 0;
        if (rowload < cnt) myidx = ind[base + rowload];
        const int nk = (cnt - half + 1) >> 1;
        int k = 0;
        for (; k + 3 < nk; k += 4) {
            const int i0 = __shfl(myidx, lbase + k);
            const int i1 = __shfl(myidx, lbase + k + 1);
            const int i2 = __shfl(myidx, lbase + k + 2);
            const int i3 = __shfl(myidx, lbase + k + 3);
            const float4 r0 = *(const float4*)(wt + (size_t)i0 * D_ + col);
            const float4 r1 = *(const float4*)(wt + (size_t)i1 * D_ + col);
            const float4 r2 = *(const float4*)(wt + (size_t)i2 * D_ + col);
            const float4 r3 = *(const float4*)(wt + (size_t)i3 * D_ + col);
            acc0.x += r0.x; acc0.y += r0.y; acc0.z += r0.z; acc0.w += r0.w;
            acc1.x += r1.x; acc1.y += r1.y; acc1.z += r1.z; acc1.w += r1.w;
            acc0.x += r2.x; acc0.y += r2.y; acc0.z += r2.z; acc0.w += r2.w;
            acc1.x += r3.x; acc1.y += r3.y; acc1.z += r3.z; acc1.w += r3.w;
        }
        for (; k < nk; ++k) {
            const int i0 = __shfl(myidx, lbase + k);
            const float4 r0 = *(const float4*)(wt + (size_t)i0 * D_ + col);
            acc0.x += r0.x; acc0.y += r0.y; acc0.z += r0.z; acc0.w += r0.w;
        }
    }

    float4 acc;
    acc.x = acc0.x + acc1.x; acc.y = acc0.y + acc1.y;
    acc.z = acc0.z + acc1.z; acc.w = acc0.w + acc1.w;
    acc.x += __shfl_down(acc.x, 32, 64);
    acc.y += __shfl_down(acc.y, 32, 64);
    acc.z += __shfl_down(acc.z, 32, 64);
    acc.w += __shfl_down(acc.w, 32, 64);
    if (half == 0)
        *(float4*)(out + ((size_t)t * B_ + bag) * D_ + col) = acc;
}

extern "C" void kernel_launch(void* const* d_in, const int* in_sizes, int n_in,
                              void* d_out, int out_size, void* d_ws, size_t ws_size,
                              hipStream_t stream) {
    const float* weights = (const float*)d_in[0];
    const int*   indices = (const int*)d_in[1];
    const int*   offsets = (const int*)d_in[2];
    float*       out     = (float*)d_out;

    const size_t ws_needed = (size_t)T_ * VP_ * 16 * sizeof(uint4);  // 6.66 MB

    if (ws_size >= ws_needed) {
        uint4* wbf = (uint4*)d_ws;
        const int conv_total  = T_ * VP_ * 16;
        const int conv_blocks = (conv_total + 255) / 256;
        convert_kernel<<<conv_blocks, 256, 0, stream>>>(weights, wbf);
        // 8 xcd-slots x 4 table-slots x 128 group-chunks; 4 waves/block, 16 bags/wave
        embag_mfma_kernel<<<8 * 4 * 128, 256, 0, stream>>>(wbf, indices, offsets, out);
    } else {
        embag_fp32_kernel<<<8 * 4 * (B_ / 4), 256, 0, stream>>>(weights, indices, offsets, out);
    }
}

// Round 3
// 363.045 us; speedup vs baseline: 1.1672x; 1.1672x over previous
//
#include <hip/hip_runtime.h>
#include <hip/hip_bf16.h>

// EmbeddingBagList: T=26, V=1000, D=128, B=8192, NNZ=409600, mode=sum, fp32.
// Round-8: round-7 (MFMA segmented-sum, verified correct) with the LDS staging
// rebuilt. Round-7's ds_write_b128 pattern was a 4-way bank conflict (7.6e7
// conflict cycles/dispatch => DS pipe ~173us/CU; kernel = DS + gather SUM).
// Fix: re-assign gather lanes so the (verified, unchanged) subtiled LDS layout
// is filled by byte address lane*16 + j*1024 — the native wave-uniform-base +
// lane*size pattern of global_load_lds. Staging now bypasses VGPRs entirely:
//   global_load_lds(wt + row(lane)*256B + slot(lane)*16B, lds + j*1024, 16B)
// (global source per-lane = gather; LDS dest linear = conflict-free DMA).
// tr-read side byte-identical to round-7: group q reads tiles G=2q,2q+1 at
// addr = base + q*2048 + s*8 (+ chunk*128, +1024 for e=4..7).

#define T_ 26
#define V_ 1000
#define VP_ 1001          // padded rows: row V_ is an all-zero sentinel
#define D_ 128
#define B_ 8192
#define NNZ_ 409600

typedef short s4v  __attribute__((ext_vector_type(4)));
typedef short s8v  __attribute__((ext_vector_type(8)));
typedef float f32x4 __attribute__((ext_vector_type(4)));
typedef unsigned int u32x4v __attribute__((ext_vector_type(4)));

__device__ __forceinline__ unsigned short f2bf(float f) {
    __hip_bfloat16 b = __float2bfloat16(f);   // RNE
    return *reinterpret_cast<unsigned short*>(&b);
}

// ---- pre-pass: fp32 weights -> bf16 rows in workspace (+ zero sentinel row) ----
__global__ __launch_bounds__(256) void convert_kernel(
    const float* __restrict__ weights, uint4* __restrict__ wbf)
{
    const int u = blockIdx.x * 256 + threadIdx.x;   // one uint4 (8 dims) per thread
    const int total = T_ * VP_ * 16;
    if (u >= total) return;
    const int s  = u & 15;              // 16B slot in row
    const int rv = (u >> 4) % VP_;      // padded row
    const int t  = u / (VP_ * 16);      // table
    uint4 pk = make_uint4(0u, 0u, 0u, 0u);
    if (rv < V_) {
        const float* src = weights + ((size_t)t * V_ + rv) * D_ + s * 8;
        const float4 a = ((const float4*)src)[0];
        const float4 b = ((const float4*)src)[1];
        pk.x = ((unsigned)f2bf(a.y) << 16) | f2bf(a.x);
        pk.y = ((unsigned)f2bf(a.w) << 16) | f2bf(a.z);
        pk.z = ((unsigned)f2bf(b.y) << 16) | f2bf(b.x);
        pk.w = ((unsigned)f2bf(b.w) << 16) | f2bf(b.z);
    }
    wbf[u] = pk;
}

// hardware transpose-read: group of 16 lanes, addr = tile_base + s*8 (linear),
// delivers column s of the [4][16] row-major bf16 tile to lane s.
#define TRRD(dst, addr, OFFLIT) \
    asm volatile("ds_read_b64_tr_b16 %0, %1 offset:" OFFLIT : "=v"(dst) : "v"(addr))

#define MFMA16(a, b, c) __builtin_amdgcn_mfma_f32_16x16x32_bf16((a), (b), (c), 0, 0, 0)
#define CAT8(lo, hi) __builtin_shufflevector((lo), (hi), 0, 1, 2, 3, 4, 5, 6, 7)

__global__ __launch_bounds__(256, 4) void embag_mfma_kernel(
    const uint4* __restrict__ wbf,       // [T, VP_, 16] bf16 rows
    const int*   __restrict__ indices,   // [T, NNZ]
    const int*   __restrict__ offsets,   // [T, B]
    float*       __restrict__ out)       // [T, B, D]
{
    // 8 KB per wave: 64 tiles of [4 rows][16 dims] bf16 (=128 B each).
    // tile(G = row>>2, c = dimchunk) at byte (G*8 + c)*128.
    __shared__ uint4 smem4[4 * 512];

    const int bid   = blockIdx.x;
    const int xcd   = bid & 7;        // dispatch round-robins blocks over 8 XCDs
    const int r_    = bid >> 3;
    const int tslot = r_ & 3;
    const int chunk = r_ >> 2;        // 0..127
    const int t     = xcd + 8 * tslot;
    if (t >= T_) return;

    const int wave = threadIdx.x >> 6;
    const int lane = threadIdx.x & 63;
    const int q    = lane >> 4;       // MFMA lane group 0..3
    const int s    = lane & 15;       // MFMA lane-in-group 0..15

    // gather roles: lane writes LDS byte lane*16 (+ j*1024) = tile byte
    // c*128 + r4*32 + h*16  ->  c = lane>>3, r4 = (lane>>1)&3, h = lane&1.
    const int r4 = (lane >> 1) & 3;               // row-within-quad this lane loads
    const int sl = ((lane >> 3) << 1) | (lane & 1); // 16B slot (dims 8*sl..8*sl+7)

    const int grp = chunk * 4 + wave; // 0..511
    const int g0  = grp * 16;         // first bag of this wave's 16-bag group

    // bag boundaries: lane i (=s) owns bag g0+i with range [lo, hi)
    const int* off = offsets + t * B_;
    const int oi = g0 + lane;
    int o_l = 0;
    if (lane <= 16) o_l = (oi < B_) ? off[oi] : NNZ_;   // off[B_] := NNZ_
    const int lo       = __shfl(o_l, s);
    const int hi       = __shfl(o_l, s + 1);
    const unsigned ulen = (unsigned)(hi - lo);
    const int wstart   = __shfl(o_l, 0);
    const int wend     = __shfl(o_l, 16);

    const uint4* wt  = wbf + (size_t)t * VP_ * 16;
    const int*   ind = indices + (size_t)t * NNZ_;

    // LDS addresses (low-32 of generic pointer = LDS byte offset; validated r7)
    const unsigned lds_base = ((unsigned)(uintptr_t)(&smem4[0])) + (wave << 13);
    const unsigned ra = lds_base + (q << 11) + (s << 3);   // tr-read base (verified)

    f32x4 acc[8];
    #pragma unroll
    for (int c = 0; c < 8; ++c) acc[c] = f32x4{0.f, 0.f, 0.f, 0.f};

    for (int wb = wstart; wb < wend; wb += 64) {
        const int p = wb + lane;
        const int myidx = (p < NNZ_) ? ind[p] : V_;   // sentinel beyond table end

        for (int kb = 0; kb < 64 && wb + kb < wend; kb += 32) {
            const int pb = wb + kb;

            // gather 32 rows x 256B directly into LDS (linear dest, no VGPR trip)
            #pragma unroll
            for (int j = 0; j < 8; ++j) {
                const int bb = __shfl(myidx, kb + 4 * j + r4);
                const uint4* gp = wt + (size_t)bb * 16 + sl;
                __builtin_amdgcn_global_load_lds(
                    (const __attribute__((address_space(1))) void*)gp,
                    (__attribute__((address_space(3))) void*)(uintptr_t)(lds_base + (unsigned)(j * 1024)),
                    16, 0, 0);
            }

            // build A mask while the DMAs fly: A[i=s][k=q*8+e] = (lo <= pb+k < hi)
            const int rel = pb + q * 8 - lo;
            u32x4v mu;
            #pragma unroll
            for (int pr = 0; pr < 4; ++pr) {
                const unsigned a0 = ((unsigned)(rel + 2 * pr)     < ulen) ? 0x00003F80u : 0u;
                const unsigned a1 = ((unsigned)(rel + 2 * pr + 1) < ulen) ? 0x3F800000u : 0u;
                mu[pr] = a0 | a1;
            }
            const s8v amask = __builtin_bit_cast(s8v, mu);

            // wait for the LDS-DMA, then transpose-read fragments
            asm volatile("s_waitcnt vmcnt(0)" ::: "memory");
            __builtin_amdgcn_sched_barrier(0);

            // chunks 0..3
            s4v u0, u1, u2, u3, u4, u5, u6, u7;
            TRRD(u0, ra, "0");    TRRD(u1, ra, "1024");
            TRRD(u2, ra, "128");  TRRD(u3, ra, "1152");
            TRRD(u4, ra, "256");  TRRD(u5, ra, "1280");
            TRRD(u6, ra, "384");  TRRD(u7, ra, "1408");
            asm volatile("s_waitcnt lgkmcnt(0)" ::: "memory");
            __builtin_amdgcn_sched_barrier(0);
            acc[0] = MFMA16(amask, CAT8(u0, u1), acc[0]);
            acc[1] = MFMA16(amask, CAT8(u2, u3), acc[1]);
            acc[2] = MFMA16(amask, CAT8(u4, u5), acc[2]);
            acc[3] = MFMA16(amask, CAT8(u6, u7), acc[3]);

            // chunks 4..7
            TRRD(u0, ra, "512");  TRRD(u1, ra, "1536");
            TRRD(u2, ra, "640");  TRRD(u3, ra, "1664");
            TRRD(u4, ra, "768");  TRRD(u5, ra, "1792");
            TRRD(u6, ra, "896");  TRRD(u7, ra, "1920");
            asm volatile("s_waitcnt lgkmcnt(0)" ::: "memory");
            __builtin_amdgcn_sched_barrier(0);
            acc[4] = MFMA16(amask, CAT8(u0, u1), acc[4]);
            acc[5] = MFMA16(amask, CAT8(u2, u3), acc[5]);
            acc[6] = MFMA16(amask, CAT8(u4, u5), acc[6]);
            acc[7] = MFMA16(amask, CAT8(u6, u7), acc[7]);
        }
    }

    // D layout (m89): col = lane&15 (dim-in-chunk), row = (lane>>4)*4 + reg (bag)
    float* outt = out + ((size_t)t * B_ + g0) * D_;
    #pragma unroll
    for (int c = 0; c < 8; ++c) {
        #pragma unroll
        for (int r2 = 0; r2 < 4; ++r2) {
            outt[(size_t)(q * 4 + r2) * D_ + c * 16 + s] = acc[c][r2];
        }
    }
}

// ---- fallback: round-3 fp32 gather (used only if ws_size is too small) ----
__global__ __launch_bounds__(256) void embag_fp32_kernel(
    const float* __restrict__ weights,
    const int*   __restrict__ indices,
    const int*   __restrict__ offsets,
    float*       __restrict__ out)
{
    const int bid   = blockIdx.x;
    const int xcd   = bid & 7;
    const int r     = bid >> 3;
    const int tslot = r & 3;
    const int chunk = r >> 2;
    const int t     = xcd + 8 * tslot;
    if (t >= T_) return;

    const int wave = threadIdx.x >> 6;
    const int lane = threadIdx.x & 63;
    const int bag  = chunk * 4 + wave;

    const int* off = offsets + t * B_;
    const int start = off[bag];
    const int end   = (bag == B_ - 1) ? NNZ_ : off[bag + 1];

    const float* wt  = weights + (size_t)t * V_ * D_;
    const int*   ind = indices + (size_t)t * NNZ_;

    const int half  = lane >> 5;
    const int dl    = lane & 31;
    const int col   = dl * 4;
    const int lbase = half << 5;

    float4 acc0 = make_float4(0.f, 0.f, 0.f, 0.f);
    float4 acc1 = make_float4(0.f, 0.f, 0.f, 0.f);

    for (int base = start; base < end; base += 64) {
        const int cnt = (end - base < 64) ? (end - base) : 64;
        const int rowload = (dl << 1) + half;
        int myidx = 0;
        if (rowload < cnt) myidx = ind[base + rowload];
        const int nk = (cnt - half + 1) >> 1;
        int k = 0;
        for (; k + 3 < nk; k += 4) {
            const int i0 = __shfl(myidx, lbase + k);
            const int i1 = __shfl(myidx, lbase + k + 1);
            const int i2 = __shfl(myidx, lbase + k + 2);
            const int i3 = __shfl(myidx, lbase + k + 3);
            const float4 r0 = *(const float4*)(wt + (size_t)i0 * D_ + col);
            const float4 r1 = *(const float4*)(wt + (size_t)i1 * D_ + col);
            const float4 r2 = *(const float4*)(wt + (size_t)i2 * D_ + col);
            const float4 r3 = *(const float4*)(wt + (size_t)i3 * D_ + col);
            acc0.x += r0.x; acc0.y += r0.y; acc0.z += r0.z; acc0.w += r0.w;
            acc1.x += r1.x; acc1.y += r1.y; acc1.z += r1.z; acc1.w += r1.w;
            acc0.x += r2.x; acc0.y += r2.y; acc0.z += r2.z; acc0.w += r2.w;
            acc1.x += r3.x; acc1.y += r3.y; acc1.z += r3.z; acc1.w += r3.w;
        }
        for (; k < nk; ++k) {
            const int i0 = __shfl(myidx, lbase + k);
            const float4 r0 = *(const float4*)(wt + (size_t)i0 * D_ + col);
            acc0.x += r0.x; acc0.y += r0.y; acc0.z += r0.z; acc0.w += r0.w;
        }
    }

    float4 acc;
    acc.x = acc0.x + acc1.x; acc.y = acc0.y + acc1.y;
    acc.z = acc0.z + acc1.z; acc.w = acc0.w + acc1.w;
    acc.x += __shfl_down(acc.x, 32, 64);
    acc.y += __shfl_down(acc.y, 32, 64);
    acc.z += __shfl_down(acc.z, 32, 64);
    acc.w += __shfl_down(acc.w, 32, 64);
    if (half == 0)
        *(float4*)(out + ((size_t)t * B_ + bag) * D_ + col) = acc;
}

extern "C" void kernel_launch(void* const* d_in, const int* in_sizes, int n_in,
                              void* d_out, int out_size, void* d_ws, size_t ws_size,
                              hipStream_t stream) {
    const float* weights = (const float*)d_in[0];
    const int*   indices = (const int*)d_in[1];
    const int*   offsets = (const int*)d_in[2];
    float*       out     = (float*)d_out;

    const size_t ws_needed = (size_t)T_ * VP_ * 16 * sizeof(uint4);  // 6.66 MB

    if (ws_size >= ws_needed) {
        uint4* wbf = (uint4*)d_ws;
        const int conv_total  = T_ * VP_ * 16;
        const int conv_blocks = (conv_total + 255) / 256;
        convert_kernel<<<conv_blocks, 256, 0, stream>>>(weights, wbf);
        // 8 xcd-slots x 4 table-slots x 128 group-chunks; 4 waves/block, 16 bags/wave
        embag_mfma_kernel<<<8 * 4 * 128, 256, 0, stream>>>(wbf, indices, offsets, out);
    } else {
        embag_fp32_kernel<<<8 * 4 * (B_ / 4), 256, 0, stream>>>(weights, indices, offsets, out);
    }
}